// Round 1
// baseline (1147.905 us; speedup 1.0000x reference)
//
#include <hip/hip_runtime.h>

#define LL 256
#define DD 512

typedef _Float16 f16;
typedef _Float16 f16x4_t __attribute__((ext_vector_type(4)));
typedef _Float16 f16x8_t __attribute__((ext_vector_type(8)));
typedef float f32x4_t __attribute__((ext_vector_type(4)));

// XOR swizzle: spreads rows across LDS banks; bijective for (row,k)->addr since
// readers/writers both derive the key from the logical row. Keeps >=8B alignment.
__device__ __forceinline__ char* swzp(char* base, unsigned row, unsigned byte) {
  return base + (byte ^ ((row & 7u) << 4));
}
__device__ __forceinline__ const char* swzp(const char* base, unsigned row, unsigned byte) {
  return base + (byte ^ ((row & 7u) << 4));
}

// ---------------- prep: Wt[e][d] = (f16) W[d][e] ----------------
__global__ void k_prep(const float* __restrict__ W, f16* __restrict__ Wt) {
  __shared__ float t[64][65];
  int bx = blockIdx.x & 7;   // e tile
  int by = blockIdx.x >> 3;  // d tile
  int tx = threadIdx.x & 63, tg = threadIdx.x >> 6;
  for (int r = tg; r < 64; r += 4)
    t[r][tx] = W[(by * 64 + r) * DD + bx * 64 + tx];
  __syncthreads();
  for (int r = tg; r < 64; r += 4)
    Wt[(bx * 64 + r) * DD + by * 64 + tx] = (f16)t[tx][r];
}

struct Smem {
  f16 A_w[256 * 256];  // 128 KiB softmaxed attention weights, swizzled rows (stride 512B)
  union {
    struct { f16 bufX[256 * 32]; f16 bufW[128 * 32]; } p0;  // phase 0 staging
    struct { f16 bufP[256 * 32]; f16 bufY[64 * 32]; } pa;   // phase A staging
    f16 yT[128 * 64];                                       // phase B staging (yT[dc][m])
  } st;
  float colred[4][64];
  float colmax[64];
  float colinv[64];
  float gp[2][256];
  float beta[256];
};

__global__ __launch_bounds__(512, 2)
void k_main(const float* __restrict__ gi, const float* __restrict__ gj,
            const f16* __restrict__ Wt, const float* __restrict__ wv,
            f16* __restrict__ slabs, float* __restrict__ out) {
  __shared__ Smem sm;
  const int tid = threadIdx.x;
  const int lane = tid & 63;
  const int wave = tid >> 6;           // 0..7
  const int wm = wave & 3, wn = wave >> 2;
  const int lq = lane & 15, lg = lane >> 4;
  const int bid = blockIdx.x;
  const int b = bid >> 1, side = bid & 1;
  const float* __restrict__ x = (side ? gj : gi) + (size_t)b * (LL * DD);
  const float* __restrict__ y = (side ? gi : gj) + (size_t)b * (LL * DD);
  f16* __restrict__ slab = slabs + (size_t)bid * (LL * DD);

  char* const AW = (char*)sm.A_w;
  char* const BX = (char*)sm.st.p0.bufX;
  char* const BW = (char*)sm.st.p0.bufW;
  char* const BP = (char*)sm.st.pa.bufP;
  char* const BY = (char*)sm.st.pa.bufY;
  char* const YT = (char*)sm.st.yT;

  // ================= phase 0: P = x @ W -> slab (f16) =================
  for (int nt = 0; nt < 4; ++nt) {
    f32x4_t acc[4][4];
#pragma unroll
    for (int mf = 0; mf < 4; ++mf)
#pragma unroll
      for (int nf = 0; nf < 4; ++nf)
        acc[mf][nf] = (f32x4_t){0.f, 0.f, 0.f, 0.f};

    for (int kt = 0; kt < 16; ++kt) {
#pragma unroll
      for (int c = tid; c < 1024; c += 512) {  // stage x tile [256][32] f32 -> f16
        int row = c >> 2, sl = c & 3;
        const float* src = x + row * DD + kt * 32 + sl * 8;
        float4 a0 = *(const float4*)src;
        float4 a1 = *(const float4*)(src + 4);
        f16x8_t v;
        v[0] = (f16)a0.x; v[1] = (f16)a0.y; v[2] = (f16)a0.z; v[3] = (f16)a0.w;
        v[4] = (f16)a1.x; v[5] = (f16)a1.y; v[6] = (f16)a1.z; v[7] = (f16)a1.w;
        *(f16x8_t*)swzp(BX, row, row * 64u + sl * 16u) = v;
      }
      {  // stage W tile [128 e][32 d] from pre-transposed f16
        int row = tid >> 2, sl = tid & 3;
        f16x8_t v = *(const f16x8_t*)(Wt + (nt * 128 + row) * DD + kt * 32 + sl * 8);
        *(f16x8_t*)swzp(BW, row, row * 64u + sl * 16u) = v;
      }
      __syncthreads();
      f16x8_t af[4], bf[4];
#pragma unroll
      for (int mf = 0; mf < 4; ++mf) {
        int row = wm * 64 + mf * 16 + lq;
        af[mf] = *(const f16x8_t*)swzp(BX, row, row * 64u + lg * 16u);
      }
#pragma unroll
      for (int nf = 0; nf < 4; ++nf) {
        int er = wn * 64 + nf * 16 + lq;
        bf[nf] = *(const f16x8_t*)swzp(BW, er, er * 64u + lg * 16u);
      }
#pragma unroll
      for (int mf = 0; mf < 4; ++mf)
#pragma unroll
        for (int nf = 0; nf < 4; ++nf)
          acc[mf][nf] = __builtin_amdgcn_mfma_f32_16x16x32_f16(af[mf], bf[nf], acc[mf][nf], 0, 0, 0);
      __syncthreads();
    }
#pragma unroll
    for (int mf = 0; mf < 4; ++mf)
#pragma unroll
      for (int nf = 0; nf < 4; ++nf)
#pragma unroll
        for (int r = 0; r < 4; ++r) {
          int row = wm * 64 + mf * 16 + lg * 4 + r;
          int col = nt * 128 + wn * 64 + nf * 16 + lq;
          slab[row * DD + col] = (f16)acc[mf][nf][r];
        }
  }
  __threadfence_block();
  __syncthreads();

  // ======== phase A: S = P @ y^T per 64-wide m tile, column softmax -> A_w ========
  for (int mt = 0; mt < 4; ++mt) {
    f32x4_t acc[4][2];
#pragma unroll
    for (int mf = 0; mf < 4; ++mf)
#pragma unroll
      for (int nf = 0; nf < 2; ++nf)
        acc[mf][nf] = (f32x4_t){0.f, 0.f, 0.f, 0.f};

    for (int kt = 0; kt < 16; ++kt) {
#pragma unroll
      for (int c = tid; c < 1024; c += 512) {  // stage P tile [256][32] (f16 direct)
        int row = c >> 2, sl = c & 3;
        f16x8_t v = *(const f16x8_t*)(slab + row * DD + kt * 32 + sl * 8);
        *(f16x8_t*)swzp(BP, row, row * 64u + sl * 16u) = v;
      }
      if (tid < 256) {  // stage y tile [64 m][32 e] f32 -> f16
        int row = tid >> 2, sl = tid & 3;
        const float* src = y + (mt * 64 + row) * DD + kt * 32 + sl * 8;
        float4 a0 = *(const float4*)src;
        float4 a1 = *(const float4*)(src + 4);
        f16x8_t v;
        v[0] = (f16)a0.x; v[1] = (f16)a0.y; v[2] = (f16)a0.z; v[3] = (f16)a0.w;
        v[4] = (f16)a1.x; v[5] = (f16)a1.y; v[6] = (f16)a1.z; v[7] = (f16)a1.w;
        *(f16x8_t*)swzp(BY, row, row * 64u + sl * 16u) = v;
      }
      __syncthreads();
      f16x8_t af[4], bf[2];
#pragma unroll
      for (int mf = 0; mf < 4; ++mf) {
        int row = wm * 64 + mf * 16 + lq;
        af[mf] = *(const f16x8_t*)swzp(BP, row, row * 64u + lg * 16u);
      }
#pragma unroll
      for (int nf = 0; nf < 2; ++nf) {
        int mr = wn * 32 + nf * 16 + lq;
        bf[nf] = *(const f16x8_t*)swzp(BY, mr, mr * 64u + lg * 16u);
      }
#pragma unroll
      for (int mf = 0; mf < 4; ++mf)
#pragma unroll
        for (int nf = 0; nf < 2; ++nf)
          acc[mf][nf] = __builtin_amdgcn_mfma_f32_16x16x32_f16(af[mf], bf[nf], acc[mf][nf], 0, 0, 0);
      __syncthreads();
    }

    // ---- softmax over l (columns of S_tile) ----
    float vm[2];
#pragma unroll
    for (int nf = 0; nf < 2; ++nf) {
      float v = -3.4e38f;
#pragma unroll
      for (int mf = 0; mf < 4; ++mf)
#pragma unroll
        for (int r = 0; r < 4; ++r) v = fmaxf(v, acc[mf][nf][r]);
      v = fmaxf(v, __shfl_xor(v, 16));
      v = fmaxf(v, __shfl_xor(v, 32));
      vm[nf] = v;
    }
    if (lane < 16) {
      sm.colred[wm][wn * 32 + lane] = vm[0];
      sm.colred[wm][wn * 32 + 16 + lane] = vm[1];
    }
    __syncthreads();
    if (tid < 64)
      sm.colmax[tid] = fmaxf(fmaxf(sm.colred[0][tid], sm.colred[1][tid]),
                             fmaxf(sm.colred[2][tid], sm.colred[3][tid]));
    __syncthreads();
#pragma unroll
    for (int nf = 0; nf < 2; ++nf) {
      float cm = sm.colmax[wn * 32 + nf * 16 + lq];
      float s = 0.f;
#pragma unroll
      for (int mf = 0; mf < 4; ++mf)
#pragma unroll
        for (int r = 0; r < 4; ++r) {
          float p = __expf(acc[mf][nf][r] - cm);
          acc[mf][nf][r] = p;
          s += p;
        }
      s += __shfl_xor(s, 16);
      s += __shfl_xor(s, 32);
      vm[nf] = s;
    }
    if (lane < 16) {
      sm.colred[wm][wn * 32 + lane] = vm[0];
      sm.colred[wm][wn * 32 + 16 + lane] = vm[1];
    }
    __syncthreads();
    if (tid < 64)
      sm.colinv[tid] = 1.f / (sm.colred[0][tid] + sm.colred[1][tid] +
                              sm.colred[2][tid] + sm.colred[3][tid]);
    __syncthreads();
#pragma unroll
    for (int nf = 0; nf < 2; ++nf) {
      int colg = mt * 64 + wn * 32 + nf * 16 + lq;
      float ci = sm.colinv[wn * 32 + nf * 16 + lq];
#pragma unroll
      for (int mf = 0; mf < 4; ++mf)
#pragma unroll
        for (int r = 0; r < 4; ++r) {
          int row = wm * 64 + mf * 16 + lg * 4 + r;
          *(f16*)swzp(AW, row, row * 512u + colg * 2u) = (f16)(acc[mf][nf][r] * ci);
        }
    }
    __syncthreads();
  }

  // ======== phase B: a = A_w @ y (dc tiles of 128), fused g partials; a -> slab ========
  float garr[4][4];
#pragma unroll
  for (int mf = 0; mf < 4; ++mf)
#pragma unroll
    for (int r = 0; r < 4; ++r) garr[mf][r] = 0.f;

  for (int dct = 0; dct < 4; ++dct) {
    f32x4_t acc[4][4];
#pragma unroll
    for (int mf = 0; mf < 4; ++mf)
#pragma unroll
      for (int nf = 0; nf < 4; ++nf)
        acc[mf][nf] = (f32x4_t){0.f, 0.f, 0.f, 0.f};

    for (int mh = 0; mh < 4; ++mh) {
      {  // stage yT[dc 0..127][m 0..63] f16 (transposed), 4 strided-coalesced reads per b64
        int dc = tid & 127, mq = tid >> 7;
#pragma unroll
        for (int q = 0; q < 4; ++q) {
          int m0 = mq * 16 + q * 4;
          const float* src = y + (size_t)(mh * 64 + m0) * DD + dct * 128 + dc;
          f16x4_t v = {(f16)src[0], (f16)src[DD], (f16)src[2 * DD], (f16)src[3 * DD]};
          *(f16x4_t*)swzp(YT, dc, dc * 128u + m0 * 2u) = v;
        }
      }
      __syncthreads();
#pragma unroll
      for (int ks = 0; ks < 2; ++ks) {
        f16x8_t af[4], bf[4];
#pragma unroll
        for (int mf = 0; mf < 4; ++mf) {
          int row = wm * 64 + mf * 16 + lq;
          af[mf] = *(const f16x8_t*)swzp(AW, row, row * 512u + (mh * 64 + ks * 32 + lg * 8) * 2u);
        }
#pragma unroll
        for (int nf = 0; nf < 4; ++nf) {
          int dcr = wn * 64 + nf * 16 + lq;
          bf[nf] = *(const f16x8_t*)swzp(YT, dcr, dcr * 128u + (ks * 32 + lg * 8) * 2u);
        }
#pragma unroll
        for (int mf = 0; mf < 4; ++mf)
#pragma unroll
          for (int nf = 0; nf < 4; ++nf)
            acc[mf][nf] = __builtin_amdgcn_mfma_f32_16x16x32_f16(af[mf], bf[nf], acc[mf][nf], 0, 0, 0);
      }
      __syncthreads();
    }
    // epilogue: a -> slab (f16), accumulate logit partials g (deterministic, no atomics)
#pragma unroll
    for (int mf = 0; mf < 4; ++mf)
#pragma unroll
      for (int r = 0; r < 4; ++r) {
        int row = wm * 64 + mf * 16 + lg * 4 + r;
        float gsum = 0.f;
#pragma unroll
        for (int nf = 0; nf < 4; ++nf) {
          int dc = dct * 128 + wn * 64 + nf * 16 + lq;
          float av = acc[mf][nf][r];
          float xv = x[row * DD + dc];
          gsum += (xv - av) * wv[dc] + (xv * av) * wv[DD + dc];
          slab[row * DD + dc] = (f16)av;
        }
        gsum += __shfl_xor(gsum, 1);
        gsum += __shfl_xor(gsum, 2);
        gsum += __shfl_xor(gsum, 4);
        gsum += __shfl_xor(gsum, 8);
        garr[mf][r] += gsum;  // valid on lq==0 lanes
      }
  }
  if (lq == 0) {
#pragma unroll
    for (int mf = 0; mf < 4; ++mf)
#pragma unroll
      for (int r = 0; r < 4; ++r) {
        int row = wm * 64 + mf * 16 + lg * 4 + r;
        sm.gp[wn][row] = garr[mf][r];
      }
  }
  __threadfence_block();
  __syncthreads();

  // ======== beta = softmax_l(g), computed by wave 0 ========
  if (wave == 0) {
    float gv[4];
    float M = -3.4e38f;
#pragma unroll
    for (int q = 0; q < 4; ++q) {
      int l = lane + q * 64;
      gv[q] = sm.gp[0][l] + sm.gp[1][l];
      M = fmaxf(M, gv[q]);
    }
#pragma unroll
    for (int s = 1; s < 64; s <<= 1) M = fmaxf(M, __shfl_xor(M, s));
    float S = 0.f;
    float ev[4];
#pragma unroll
    for (int q = 0; q < 4; ++q) { ev[q] = __expf(gv[q] - M); S += ev[q]; }
#pragma unroll
    for (int s = 1; s < 64; s <<= 1) S += __shfl_xor(S, s);
    float inv = 1.f / S;
#pragma unroll
    for (int q = 0; q < 4; ++q) sm.beta[lane + q * 64] = ev[q] * inv;
  }
  __syncthreads();

  // ======== pooled output: out = [sum_l b*(x-a), sum_l b*(x*a)] ========
  {
    int dc = tid;  // 0..511
    float s1 = 0.f, s2 = 0.f;
    for (int l = 0; l < 256; ++l) {
      float bl = sm.beta[l];
      float av = (float)slab[l * DD + dc];
      float xv = x[l * DD + dc];
      s1 += bl * (xv - av);
      s2 += bl * (xv * av);
    }
    size_t o = (size_t)side * (512u * 1024u) + (size_t)b * 1024u;
    out[o + dc] = s1;
    out[o + DD + dc] = s2;
  }
}

extern "C" void kernel_launch(void* const* d_in, const int* in_sizes, int n_in,
                              void* d_out, int out_size, void* d_ws, size_t ws_size,
                              hipStream_t stream) {
  (void)in_sizes; (void)n_in; (void)out_size; (void)ws_size;
  const float* gi = (const float*)d_in[0];
  const float* gj = (const float*)d_in[1];
  const float* W  = (const float*)d_in[2];
  const float* wv = (const float*)d_in[3];
  float* out = (float*)d_out;
  f16* Wt = (f16*)d_ws;                 // 512x512 f16 = 512 KiB
  f16* slabs = Wt + DD * DD;            // 1024 slabs x 256 KiB (P, later reused for a)
  k_prep<<<dim3(64), dim3(256), 0, stream>>>(W, Wt);
  k_main<<<dim3(1024), dim3(512), 0, stream>>>(gi, gj, Wt, wv, slabs, out);
}